// Round 2
// baseline (1299.952 us; speedup 1.0000x reference)
//
#include <hip/hip_runtime.h>

#define B_ 2
#define L_ 2048
#define D_ 1024
#define H_ 16
#define DK_ 64

typedef __bf16 bf16x8 __attribute__((ext_vector_type(8)));
typedef short s16x8 __attribute__((ext_vector_type(8)));
typedef float f32x4 __attribute__((ext_vector_type(4)));

__device__ inline f32x4 mfma_bf16(s16x8 a, s16x8 b, f32x4 c) {
    return __builtin_amdgcn_mfma_f32_16x16x32_bf16(
        __builtin_bit_cast(bf16x8, a), __builtin_bit_cast(bf16x8, b), c, 0, 0, 0);
}

__device__ inline unsigned short f2bf(float f) {
    unsigned int x = __builtin_bit_cast(unsigned int, f);
    unsigned int r = (x + 0x7fffu + ((x >> 16) & 1u)) >> 16;
    return (unsigned short)r;
}

// load 8 consecutive f32, round-to-nearest-even to bf16x8 (carried as s16x8)
__device__ inline s16x8 cvt8(const float* __restrict__ p) {
    s16x8 r;
#pragma unroll
    for (int j = 0; j < 8; ++j) r[j] = (short)f2bf(p[j]);
    return r;
}

// ------- weight transpose + cast: dst_bf16[n][k] = src_f32[k][n], 1024x1024 --
__global__ __launch_bounds__(256) void transpose_w(const float* __restrict__ src,
                                                   unsigned short* __restrict__ dst) {
    int idx = blockIdx.x * 256 + threadIdx.x;   // 1M elements
    int k = idx >> 10, n = idx & 1023;
    dst[n * 1024 + k] = f2bf(src[idx]);
}

// ------- GEMM: C[4096x1024] = Xf32[4096x1024] @ W (given as bf16 WT[n][k]) --
// MODE 0: store bf16 as [b][h][l][dk]   (qh / kh)
// MODE 1: store bf16 as [b][h][dv][l]   (v transposed)
template <int MODE>
__global__ __launch_bounds__(256) void gemm_f32a(const float* __restrict__ X,
                                                 const unsigned short* __restrict__ WT,
                                                 unsigned short* __restrict__ out) {
    int wave = threadIdx.x >> 6;
    int lane = threadIdx.x & 63;
    int l15 = lane & 15, quad = lane >> 4;
    int mrow = blockIdx.x * 64 + wave * 16 + l15;      // A-frag row
    int ntbase = blockIdx.y * 64;

    const float* aptr = X + mrow * 1024 + quad * 8;
    f32x4 acc[4];
#pragma unroll
    for (int d = 0; d < 4; ++d) acc[d] = (f32x4){0.f, 0.f, 0.f, 0.f};

    for (int k0 = 0; k0 < 1024; k0 += 32) {
        s16x8 a = cvt8(aptr + k0);
#pragma unroll
        for (int d = 0; d < 4; ++d) {
            const unsigned short* bptr = WT + (ntbase + d * 16 + l15) * 1024 + k0 + quad * 8;
            acc[d] = mfma_bf16(a, *(const s16x8*)bptr, acc[d]);
        }
    }

    int mbase = blockIdx.x * 64 + wave * 16 + quad * 4;   // C rows: mbase + r
#pragma unroll
    for (int d = 0; d < 4; ++d) {
        int ncol = ntbase + d * 16 + l15;
#pragma unroll
        for (int r = 0; r < 4; ++r) {
            int m = mbase + r;
            float vv = acc[d][r];
            int b = m >> 11, l = m & 2047, h = ncol >> 6, dd = ncol & 63;
            if (MODE == 0) {
                out[(((b * H_ + h) * L_) + l) * DK_ + dd] = f2bf(vv);
            } else {
                out[(((b * H_ + h) * DK_) + dd) * L_ + l] = f2bf(vv);
            }
        }
    }
}

// ------- out-proj GEMM: pre_f32[4096x1024] = ctx_bf16 @ Wo (bf16 WT[n][k]) --
__global__ __launch_bounds__(256) void gemm_bf16a(const unsigned short* __restrict__ X,
                                                  const unsigned short* __restrict__ WT,
                                                  float* __restrict__ out) {
    int wave = threadIdx.x >> 6;
    int lane = threadIdx.x & 63;
    int l15 = lane & 15, quad = lane >> 4;
    int mrow = blockIdx.x * 64 + wave * 16 + l15;
    int ntbase = blockIdx.y * 64;

    const unsigned short* aptr = X + mrow * 1024 + quad * 8;
    f32x4 acc[4];
#pragma unroll
    for (int d = 0; d < 4; ++d) acc[d] = (f32x4){0.f, 0.f, 0.f, 0.f};

    for (int k0 = 0; k0 < 1024; k0 += 32) {
        s16x8 a = *(const s16x8*)(aptr + k0);
#pragma unroll
        for (int d = 0; d < 4; ++d) {
            const unsigned short* bptr = WT + (ntbase + d * 16 + l15) * 1024 + k0 + quad * 8;
            acc[d] = mfma_bf16(a, *(const s16x8*)bptr, acc[d]);
        }
    }

    int mbase = blockIdx.x * 64 + wave * 16 + quad * 4;
#pragma unroll
    for (int d = 0; d < 4; ++d) {
        int ncol = ntbase + d * 16 + l15;
#pragma unroll
        for (int r = 0; r < 4; ++r)
            out[(mbase + r) * 1024 + ncol] = acc[d][r];
    }
}

// ------- attention: block = (b,h, 64 q-rows); wave = 16 q-rows -------------
__global__ __launch_bounds__(256) void attn_kernel(const unsigned short* __restrict__ qh,
                                                   const unsigned short* __restrict__ kh,
                                                   const unsigned short* __restrict__ vt,
                                                   const int* __restrict__ mask,
                                                   float* __restrict__ attn,
                                                   unsigned short* __restrict__ ctx) {
    __shared__ unsigned short pbuf[4][16][32];   // per-wave P tile (16 q x 32 k)
    int wave = threadIdx.x >> 6, lane = threadIdx.x & 63;
    int l15 = lane & 15, quad = lane >> 4;
    int bh = blockIdx.x >> 5;         // b*16+h
    int qt = blockIdx.x & 31;
    int b = bh >> 4;
    int q0 = qt * 64 + wave * 16;

    const unsigned short* Q = qh + (bh * L_ + q0 + l15) * DK_ + quad * 8;
    const unsigned short* K = kh + (size_t)bh * L_ * DK_;
    s16x8 a0 = *(const s16x8*)(Q);
    s16x8 a1 = *(const s16x8*)(Q + 32);

    const int* mrow[4];
#pragma unroll
    for (int r = 0; r < 4; ++r)
        mrow[r] = mask + (size_t)(b * L_ + q0 + quad * 4 + r) * L_;

    // ---- pass 1: per-lane online max/sum over this lane's column subset ----
    float m_l[4], l_l[4];
#pragma unroll
    for (int r = 0; r < 4; ++r) { m_l[r] = -1e30f; l_l[r] = 0.f; }

    for (int kt = 0; kt < 128; ++kt) {
        int col = kt * 16 + l15;
        const unsigned short* Kp = K + col * DK_ + quad * 8;
        f32x4 acc = (f32x4){0.f, 0.f, 0.f, 0.f};
        acc = mfma_bf16(a0, *(const s16x8*)Kp, acc);
        acc = mfma_bf16(a1, *(const s16x8*)(Kp + 32), acc);
#pragma unroll
        for (int r = 0; r < 4; ++r) {
            float sv = mrow[r][col] ? acc[r] * 0.125f : -1e9f;
            float mo = m_l[r];
            float mn = fmaxf(mo, sv);
            l_l[r] = l_l[r] * __expf(mo - mn) + __expf(sv - mn);
            m_l[r] = mn;
        }
    }
    // merge (m,l) across the 16 lanes of the quad-group
    float Mf[4], inv_l[4];
#pragma unroll
    for (int r = 0; r < 4; ++r) {
        float mM = m_l[r];
        mM = fmaxf(mM, __shfl_xor(mM, 1));
        mM = fmaxf(mM, __shfl_xor(mM, 2));
        mM = fmaxf(mM, __shfl_xor(mM, 4));
        mM = fmaxf(mM, __shfl_xor(mM, 8));
        float la = l_l[r] * __expf(m_l[r] - mM);
        la += __shfl_xor(la, 1);
        la += __shfl_xor(la, 2);
        la += __shfl_xor(la, 4);
        la += __shfl_xor(la, 8);
        Mf[r] = mM;
        inv_l[r] = 1.0f / la;
    }

    // ---- pass 2: recompute S, write attn (f32), accumulate PV ----
    float* arow[4];
#pragma unroll
    for (int r = 0; r < 4; ++r)
        arow[r] = attn + ((size_t)bh * L_ + q0 + quad * 4 + r) * L_;

    f32x4 oacc[4];
#pragma unroll
    for (int d = 0; d < 4; ++d) oacc[d] = (f32x4){0.f, 0.f, 0.f, 0.f};

    for (int c = 0; c < 64; ++c) {
        int n0 = c * 32;
#pragma unroll
        for (int t = 0; t < 2; ++t) {
            int col = n0 + t * 16 + l15;
            const unsigned short* Kp = K + col * DK_ + quad * 8;
            f32x4 acc = (f32x4){0.f, 0.f, 0.f, 0.f};
            acc = mfma_bf16(a0, *(const s16x8*)Kp, acc);
            acc = mfma_bf16(a1, *(const s16x8*)(Kp + 32), acc);
#pragma unroll
            for (int r = 0; r < 4; ++r) {
                float sv = mrow[r][col] ? acc[r] * 0.125f : -1e9f;
                float p = __expf(sv - Mf[r]) * inv_l[r];
                arow[r][col] = p;
                pbuf[wave][quad * 4 + r][t * 16 + l15] = f2bf(p);
            }
        }
        __syncthreads();
        s16x8 pa = *(const s16x8*)&pbuf[wave][l15][quad * 8];
#pragma unroll
        for (int d = 0; d < 4; ++d) {
            const unsigned short* Vp = vt + ((size_t)bh * DK_ + d * 16 + l15) * L_ + n0 + quad * 8;
            oacc[d] = mfma_bf16(pa, *(const s16x8*)Vp, oacc[d]);
        }
        __syncthreads();
    }

    // ctx[b][l][h*64+dv] bf16
    int h = bh & 15;
#pragma unroll
    for (int d = 0; d < 4; ++d) {
#pragma unroll
        for (int r = 0; r < 4; ++r) {
            int l = q0 + quad * 4 + r;
            ctx[((size_t)(b * L_ + l)) * 1024 + h * 64 + d * 16 + l15] = f2bf(oacc[d][r]);
        }
    }
}

// ---------------- layernorm(pre + residual), all f32 ----------------
__global__ __launch_bounds__(256) void ln_kernel(const float* __restrict__ pre,
                                                 const float* __restrict__ resid,
                                                 const float* __restrict__ g,
                                                 const float* __restrict__ beta,
                                                 float* __restrict__ out) {
    int row = blockIdx.x;
    int tid = threadIdx.x;
    const float* pr = pre + (size_t)row * 1024;
    const float* rr = resid + (size_t)row * 1024;
    float x[4], s = 0.f, sq = 0.f;
#pragma unroll
    for (int i = 0; i < 4; ++i) {
        int idx = tid + i * 256;
        x[i] = pr[idx] + rr[idx];
        s += x[i];
        sq += x[i] * x[i];
    }
    s += __shfl_xor(s, 1);  sq += __shfl_xor(sq, 1);
    s += __shfl_xor(s, 2);  sq += __shfl_xor(sq, 2);
    s += __shfl_xor(s, 4);  sq += __shfl_xor(sq, 4);
    s += __shfl_xor(s, 8);  sq += __shfl_xor(sq, 8);
    s += __shfl_xor(s, 16); sq += __shfl_xor(sq, 16);
    s += __shfl_xor(s, 32); sq += __shfl_xor(sq, 32);
    __shared__ float ssum[4], ssq[4];
    if ((tid & 63) == 0) { ssum[tid >> 6] = s; ssq[tid >> 6] = sq; }
    __syncthreads();
    s = ssum[0] + ssum[1] + ssum[2] + ssum[3];
    sq = ssq[0] + ssq[1] + ssq[2] + ssq[3];
    float mean = s * (1.0f / 1024.0f);
    float var = sq * (1.0f / 1024.0f) - mean * mean;
    float rstd = rsqrtf(var + 1e-6f);
#pragma unroll
    for (int i = 0; i < 4; ++i) {
        int idx = tid + i * 256;
        out[(size_t)row * 1024 + idx] = (x[i] - mean) * rstd * g[idx] + beta[idx];
    }
}

extern "C" void kernel_launch(void* const* d_in, const int* in_sizes, int n_in,
                              void* d_out, int out_size, void* d_ws, size_t ws_size,
                              hipStream_t stream) {
    const float* q   = (const float*)d_in[0];
    const float* k   = (const float*)d_in[1];
    const float* v   = (const float*)d_in[2];
    const int*   msk = (const int*)d_in[3];
    const float* w_q = (const float*)d_in[4];
    const float* w_k = (const float*)d_in[5];
    const float* w_v = (const float*)d_in[6];
    const float* w_o = (const float*)d_in[7];
    const float* lng = (const float*)d_in[8];
    const float* lnb = (const float*)d_in[9];

    char* ws = (char*)d_ws;
    unsigned short* wqT = (unsigned short*)(ws + 0 * (1u << 21));
    unsigned short* wkT = (unsigned short*)(ws + 1 * (1u << 21));
    unsigned short* wvT = (unsigned short*)(ws + 2 * (1u << 21));
    unsigned short* woT = (unsigned short*)(ws + 3 * (1u << 21));
    unsigned short* qh  = (unsigned short*)(ws + (8u << 20));
    unsigned short* kh  = (unsigned short*)(ws + (16u << 20));
    unsigned short* vt  = (unsigned short*)(ws + (24u << 20));
    unsigned short* ctx = (unsigned short*)(ws + (32u << 20));
    float*          pre = (float*)(ws + (8u << 20));   // overlays qh/kh (dead)

    float* outp = (float*)d_out;
    float* attn = outp + (size_t)B_ * L_ * D_;

    transpose_w<<<4096, 256, 0, stream>>>(w_q, wqT);
    transpose_w<<<4096, 256, 0, stream>>>(w_k, wkT);
    transpose_w<<<4096, 256, 0, stream>>>(w_v, wvT);
    transpose_w<<<4096, 256, 0, stream>>>(w_o, woT);

    dim3 g1(64, 16);
    gemm_f32a<0><<<g1, 256, 0, stream>>>(q, wqT, qh);
    gemm_f32a<0><<<g1, 256, 0, stream>>>(k, wkT, kh);
    gemm_f32a<1><<<g1, 256, 0, stream>>>(v, wvT, vt);

    attn_kernel<<<1024, 256, 0, stream>>>(qh, kh, vt, msk, attn, ctx);

    gemm_bf16a<<<g1, 256, 0, stream>>>(ctx, woT, pre);

    ln_kernel<<<4096, 256, 0, stream>>>(pre, q, lng, lnb, outp);
}